// Round 1
// baseline (305.526 us; speedup 1.0000x reference)
//
#include <hip/hip_runtime.h>

// PositionId gather: out[t, :] = buffer[t - offsets[seg(t)], :]
// buffer: [8192, 1024] fp32, offsets: [17] int32, out: [65536, 1024] fp32.

#define D_MODEL 1024
#define VEC4_PER_ROW (D_MODEL / 4)   // 256 float4 per row
#define MAX_OFFSETS 64               // generous upper bound for unrolled scan

__global__ __launch_bounds__(256) void positionid_gather(
    const float4* __restrict__ buf,      // [MAX_SEQLEN, 256] as float4
    const int*    __restrict__ offsets,  // [n_off]
    int n_off,                           // number of offset entries (BATCH+1)
    float4*       __restrict__ out)      // [T, 256] as float4
{
    const int t = blockIdx.x;            // token row

    // Wave-uniform linear scan: seg = max i such that offsets[i] <= t, i in [0, n_off-2]
    int seg = 0;
    #pragma unroll 4
    for (int i = 1; i < n_off - 1; ++i) {
        if (offsets[i] <= t) seg = i;
    }
    const int pos = t - offsets[seg];

    out[(size_t)t * VEC4_PER_ROW + threadIdx.x] =
        buf[(size_t)pos * VEC4_PER_ROW + threadIdx.x];
}

extern "C" void kernel_launch(void* const* d_in, const int* in_sizes, int n_in,
                              void* d_out, int out_size, void* d_ws, size_t ws_size,
                              hipStream_t stream) {
    const float4* buf     = (const float4*)d_in[0];
    const int*    offsets = (const int*)d_in[1];
    const int     n_off   = in_sizes[1];          // 17
    float4*       out     = (float4*)d_out;

    const int T = out_size / D_MODEL;             // 65536 token rows

    positionid_gather<<<dim3(T), dim3(256), 0, stream>>>(buf, offsets, n_off, out);
}